// Round 7
// baseline (261.925 us; speedup 1.0000x reference)
//
#include <hip/hip_runtime.h>
#include <hip/hip_bf16.h>

#define NB 2
#define NL 2048
#define NH 12
#define ND 64
#define NEWTON 6
#define WV 8            // waves per block (attn)
#define TPW 16          // key-tiles per wave = 128/WV

typedef __bf16 bf16x8 __attribute__((ext_vector_type(8)));
typedef float f32x4 __attribute__((ext_vector_type(4)));
typedef float f32x2 __attribute__((ext_vector_type(2)));

// DPP row_ror reductions within each 16-lane row.
#define ROR_ADD(v, n)                                                         \
  (v) += __int_as_float(__builtin_amdgcn_update_dpp(                          \
      0, __float_as_int(v), 0x120 + (n), 0xF, 0xF, true))
#define ROR_MAX(v, n)                                                         \
  (v) = fmaxf((v), __int_as_float(__builtin_amdgcn_update_dpp(                \
                  0, __float_as_int(v), 0x120 + (n), 0xF, 0xF, true)))

__device__ __forceinline__ void split_bf16(float f, __bf16& hi, __bf16& lo) {
  __bf16 h = (__bf16)f;
  hi = h;
  lo = (__bf16)(f - (float)h);
}

// ---- prep: block = (b, kt16, head-group of 4) x {K,V}. 1536 blocks, 256 thr,
// 16.6 KB LDS. K-blocks and V-blocks are independent for 2x parallelism.
__global__ __launch_bounds__(256) void prep(
    const float* __restrict__ kg, const float* __restrict__ vg,
    __bf16* __restrict__ kp_hi, __bf16* __restrict__ kp_lo,
    __bf16* __restrict__ vp_hi, __bf16* __restrict__ vp_lo) {
  __shared__ __align__(16) float kv[16][260];  // [key][4 heads x 64 d]
  const int blk = blockIdx.x;
  const int isV = blk >= NB * 128 * 3;
  const int bk = isV ? blk - NB * 128 * 3 : blk;
  const int hg = bk % 3;
  const int kt = (bk / 3) & 127;
  const int b = bk / 384;
  const int t = threadIdx.x;
  const int w = t >> 6;           // wave 0..3 == local head
  const int lane = t & 63;
  const int quad = lane >> 4;
  const int l16 = lane & 15;

  const float* __restrict__ src = isV ? vg : kg;
#pragma unroll
  for (int i = 0; i < 4; ++i) {
    const int f = i * 1024 + t * 4;
    const int key = f >> 8;
    const int rem = f & 255;
    const size_t s =
        (size_t)(b * NL + kt * 16 + key) * (NH * ND) + hg * 256 + rem;
    *(f32x4*)(&kv[key][rem]) = *(const f32x4*)(src + s);
  }
  __syncthreads();

  const int h = hg * 4 + w;

  if (!isV) {
    // ---- K pack ----
    const float* p = &kv[l16][w * 64 + quad * 8];
    f32x4 a0 = *(const f32x4*)(p);
    f32x4 a1 = *(const f32x4*)(p + 4);
    f32x4 a2 = *(const f32x4*)(p + 32);
    f32x4 a3 = *(const f32x4*)(p + 36);
    bf16x8 h0, l0, h1, l1;
#pragma unroll
    for (int j = 0; j < 4; ++j) {
      __bf16 hb, lb;
      split_bf16(a0[j], hb, lb); h0[j] = hb;     l0[j] = lb;
      split_bf16(a1[j], hb, lb); h0[4 + j] = hb; l0[4 + j] = lb;
      split_bf16(a2[j], hb, lb); h1[j] = hb;     l1[j] = lb;
      split_bf16(a3[j], hb, lb); h1[4 + j] = hb; l1[4 + j] = lb;
    }
    const size_t basek =
        ((size_t)((b * NH + h) * 128 + kt) * 2) * 512 + lane * 8;
    *(bf16x8*)(kp_hi + basek) = h0;
    *(bf16x8*)(kp_lo + basek) = l0;
    *(bf16x8*)(kp_hi + basek + 512) = h1;
    *(bf16x8*)(kp_lo + basek + 512) = l1;
  } else {
    // ---- V pack ----
    const int halfsel = (kt >> 3) & 1;
    const int pi = (kt >> 4) * 8 + (kt & 7);
    const int q2 = quad & 1;
    const int nhalf = quad >> 1;
    const int qdst = 2 * halfsel + q2;
#pragma unroll
    for (int nn = 0; nn < 2; ++nn) {
      const int n = nhalf * 2 + nn;
      bf16x8 hv, lv;
#pragma unroll
      for (int j = 0; j < 8; ++j) {
        __bf16 hb, lb;
        split_bf16(kv[q2 * 8 + j][w * 64 + n * 16 + l16], hb, lb);
        hv[j] = hb;
        lv[j] = lb;
      }
      const size_t off =
          ((((size_t)(b * NH + h) * 64 + pi) * 4 + n) * 64 + qdst * 16 + l16) * 8;
      *(bf16x8*)(vp_hi + off) = hv;
      *(bf16x8*)(vp_lo + off) = lv;
    }
  }
}

// ---------------- main fused attention-poly kernel ----------------
// launch_bounds(512, 2): budget 256 regs -> the MFMA even-split heuristic caps
// arch VGPR at 128 (vs 64 under (512,4)), so y[16][2] + temps (~124 regs) fit
// entirely in arch VGPRs -> no v_accvgpr shuttle in the Newton loop.
// Residency stays 2 blocks/CU as long as total allocation <= 128; the
// asm("":::"memory") fences below stop the scheduler from inflating pressure
// with hoisted loads now that the budget is loose.
// History: (512,4) -> forced 64V/64A split, y parked in AGPRs (rounds 0-4,6);
// (512,6) -> cap 85, y spilled to scratch, 594MB traffic (round 5).
__launch_bounds__(512, 2)
__global__ void attn_poly(const float* __restrict__ qg,
                          const __bf16* __restrict__ kp_hi,
                          const __bf16* __restrict__ kp_lo,
                          const __bf16* __restrict__ vp_hi,
                          const __bf16* __restrict__ vp_lo,
                          float* __restrict__ outg) {
  // Half-keyspace weight slab W[16 rows][1024 keys] bf16, XOR-swizzled
  // (byte ^= (row&7)<<4). Phases 4/5 run twice (keys 0-1023, 1024-2047).
  // 35.5 KB total LDS; overlaid with the phase-6 partial slab.
  __shared__ __align__(16) union ShMem {
    __bf16 wslab[16][1024];      // 32 KB, phases 4-5 (one key-half)
    float ex[WV][16][68];        // 34.8 KB, phase 6
  } sh;
  __shared__ float redmax[WV][17];
  __shared__ float redn[NEWTON][16][2];   // per-iteration atomic sum buffers

  const int tid = threadIdx.x;
  const int w = tid >> 6;
  const int lane = tid & 63;
  const int quad = lane >> 4;
  const int l16 = lane & 15;

  // XCD-aware swizzle: blocks dispatch round-robin over 8 XCDs (blk&7).
  // Give each XCD 3 complete bh groups (24 bh / 8 XCD) so the concurrent
  // block window on an XCD stays within one bh -> K/V (2MB) L2-resident.
  // Bijective: 3072 = 8 * 384, 384 = 3 * 128.
  const int blk = blockIdx.x;
  const int xcd = blk & 7;
  const int slot = blk >> 3;           // 0..383 within this XCD
  const int bh = xcd * 3 + (slot >> 7);
  const int qt = slot & 127;
  const int h = bh % NH;
  const int b = bh / NH;
  const int qbase = qt * 16;

  // ---- Q fragments: fp32 * 0.125 -> bf16 hi/lo ----
  bf16x8 qhi0, qlo0, qhi1, qlo1;
  {
    const float* qp = qg + ((b * NL + qbase + l16) * NH + h) * ND + quad * 8;
    f32x4 a0 = *(const f32x4*)(qp);
    f32x4 a1 = *(const f32x4*)(qp + 4);
    f32x4 a2 = *(const f32x4*)(qp + 32);
    f32x4 a3 = *(const f32x4*)(qp + 36);
#pragma unroll
    for (int j = 0; j < 4; ++j) {
      __bf16 hb, lb;
      split_bf16(a0[j] * 0.125f, hb, lb); qhi0[j] = hb;     qlo0[j] = lb;
      split_bf16(a1[j] * 0.125f, hb, lb); qhi0[4 + j] = hb; qlo0[4 + j] = lb;
      split_bf16(a2[j] * 0.125f, hb, lb); qhi1[j] = hb;     qlo1[j] = lb;
      split_bf16(a3[j] * 0.125f, hb, lb); qhi1[4 + j] = hb; qlo1[4 + j] = lb;
    }
  }

  // ---- phase 1: S = (Q/8) Kt ; y[t][j] = rows (quad*4+2j, +2j+1), col l16 ----
  // y holds raw scores here; converted to y = negc0 - s after the max phase,
  // then updated in place by the Newton corrections.
  f32x2 y[TPW][2];
  {
    const __bf16* kbh = kp_hi + (size_t)bh * 131072;
    const __bf16* kbl = kp_lo + (size_t)bh * 131072;
#pragma unroll
    for (int t = 0; t < TPW; ++t) {
      const int ktile = w + WV * t;
      const size_t o = (size_t)ktile * 1024 + lane * 8;
      bf16x8 khi0 = *(const bf16x8*)(kbh + o);
      bf16x8 khi1 = *(const bf16x8*)(kbh + o + 512);
      bf16x8 klo0 = *(const bf16x8*)(kbl + o);
      bf16x8 klo1 = *(const bf16x8*)(kbl + o + 512);
      f32x4 acc = {0.f, 0.f, 0.f, 0.f};
      acc = __builtin_amdgcn_mfma_f32_16x16x32_bf16(qhi0, khi0, acc, 0, 0, 0);
      acc = __builtin_amdgcn_mfma_f32_16x16x32_bf16(qhi1, khi1, acc, 0, 0, 0);
      acc = __builtin_amdgcn_mfma_f32_16x16x32_bf16(qhi0, klo0, acc, 0, 0, 0);
      acc = __builtin_amdgcn_mfma_f32_16x16x32_bf16(qhi1, klo1, acc, 0, 0, 0);
      acc = __builtin_amdgcn_mfma_f32_16x16x32_bf16(qlo0, khi0, acc, 0, 0, 0);
      acc = __builtin_amdgcn_mfma_f32_16x16x32_bf16(qlo1, khi1, acc, 0, 0, 0);
      y[t][0] = __builtin_shufflevector(acc, acc, 0, 1);
      y[t][1] = __builtin_shufflevector(acc, acc, 2, 3);
      // Pressure fence: stop the scheduler hoisting more than ~2 tiles of
      // K-loads ahead (keeps total regs <= 128 -> 2 blocks/CU).
      if ((t & 1) == 1) asm volatile("" ::: "memory");
    }
  }

  // ---- phase 2: row max -> negc[j] = -c0 pairs (= max + 1); y := negc - s ----
  {
    f32x2 mx2[2] = {y[0][0], y[0][1]};
#pragma unroll
    for (int t = 1; t < TPW; ++t) {
#pragma unroll
      for (int j = 0; j < 2; ++j) {
        mx2[j].x = fmaxf(mx2[j].x, y[t][j].x);
        mx2[j].y = fmaxf(mx2[j].y, y[t][j].y);
      }
    }
#pragma unroll
    for (int j = 0; j < 2; ++j) {
      ROR_MAX(mx2[j].x, 8); ROR_MAX(mx2[j].x, 4); ROR_MAX(mx2[j].x, 2); ROR_MAX(mx2[j].x, 1);
      ROR_MAX(mx2[j].y, 8); ROR_MAX(mx2[j].y, 4); ROR_MAX(mx2[j].y, 2); ROR_MAX(mx2[j].y, 1);
    }
    if (l16 < 4) {
      float v = (l16 == 0) ? mx2[0].x : (l16 == 1) ? mx2[0].y
              : (l16 == 2) ? mx2[1].x : mx2[1].y;
      redmax[w][quad * 4 + l16] = v;
    }
    // zero the Newton atomic buffers under the same barrier
    if (tid < NEWTON * 16 * 2) ((float*)redn)[tid] = 0.f;
    __syncthreads();
    f32x2 negc[2];
#pragma unroll
    for (int r = 0; r < 4; ++r) {
      float m = redmax[l16 & 7][quad * 4 + r];
      ROR_MAX(m, 4); ROR_MAX(m, 2); ROR_MAX(m, 1);
      ((float*)negc)[r] = m + 1.0f;            // -c0 = max + 1
    }
    // convert scores -> y0 = negc0 - s  (in place)
#pragma unroll
    for (int t = 0; t < TPW; ++t) {
      y[t][0] = negc[0] - y[t][0];
      y[t][1] = negc[1] - y[t][1];
    }
  }

  // ---- phase 3: Newton x6 on c (packed-f32 inner loop; cross-wave via ds_add) ----
  for (int it = 0; it < NEWTON; ++it) {
    f32x2 ps2[2] = {{0.f, 0.f}, {0.f, 0.f}};
    f32x2 psd2[2] = {{0.f, 0.f}, {0.f, 0.f}};
#pragma unroll
    for (int t = 0; t < TPW; ++t) {
#pragma unroll
      for (int j = 0; j < 2; ++j) {
        f32x2 v = y[t][j];                     // y >= 1 along Newton path
        float z = __builtin_amdgcn_rcpf(v.x * v.y);
        f32x2 r1 = z * __builtin_shufflevector(v, v, 1, 0);  // (1/y.x, 1/y.y)
        f32x2 r2;
        asm("v_pk_mul_f32 %0, %1, %1" : "=v"(r2) : "v"(r1));
        asm("v_pk_add_f32 %0, %0, %1" : "+v"(ps2[j]) : "v"(r2));
        asm("v_pk_fma_f32 %0, %1, %2, %0" : "+v"(psd2[j]) : "v"(r2), "v"(r1));
      }
    }
#pragma unroll
    for (int j = 0; j < 2; ++j) {
      ROR_ADD(ps2[j].x, 8);  ROR_ADD(ps2[j].x, 4);  ROR_ADD(ps2[j].x, 2);  ROR_ADD(ps2[j].x, 1);
      ROR_ADD(ps2[j].y, 8);  ROR_ADD(ps2[j].y, 4);  ROR_ADD(ps2[j].y, 2);  ROR_ADD(ps2[j].y, 1);
      ROR_ADD(psd2[j].x, 8); ROR_ADD(psd2[j].x, 4); ROR_ADD(psd2[j].x, 2); ROR_ADD(psd2[j].x, 1);
      ROR_ADD(psd2[j].y, 8); ROR_ADD(psd2[j].y, 4); ROR_ADD(psd2[j].y, 2); ROR_ADD(psd2[j].y, 1);
    }
    if (l16 < 4) {
      float a = (l16 == 0) ? ps2[0].x : (l16 == 1) ? ps2[0].y
              : (l16 == 2) ? ps2[1].x : ps2[1].y;
      float d = (l16 == 0) ? psd2[0].x : (l16 == 1) ? psd2[0].y
              : (l16 == 2) ? psd2[1].x : psd2[1].y;
      atomicAdd(&redn[it][quad * 4 + l16][0], a);
      atomicAdd(&redn[it][quad * 4 + l16][1], d);
    }
    __syncthreads();
    f32x2 dd[2];
#pragma unroll
    for (int r = 0; r < 4; ++r) {
      const f32x2 v = *(const f32x2*)(&redn[it][quad * 4 + r][0]);
      ((float*)dd)[r] =
          (v.x - 1.0f) * __builtin_amdgcn_rcpf(2.0f * v.y + 1e-8f);
    }
#pragma unroll
    for (int t = 0; t < TPW; ++t) {
      y[t][0] += dd[0];
      y[t][1] += dd[1];
    }
  }

  // ---- phases 4+5, two key-halves: materialize half the weights into the
  // 32KB swizzled slab, then consume it with V-MFMAs; repeat for the other
  // half. Tiles t = hh*8 .. hh*8+7 cover keys [hh*1024, hh*1024+1024).
  f32x4 oacc[4];
#pragma unroll
  for (int n = 0; n < 4; ++n) oacc[n] = (f32x4){0.f, 0.f, 0.f, 0.f};
  const __bf16* vpbh = vp_hi + (size_t)bh * 131072;
  const __bf16* vpbl = vp_lo + (size_t)bh * 131072;
  char* slab = (char*)&sh.wslab[0][0];

#pragma unroll
  for (int hh = 0; hh < 2; ++hh) {
    if (hh) __syncthreads();   // half-A reads complete before overwrite

    // ---- phase 4 (half): weights for tiles hh*8 .. hh*8+7 ----
#pragma unroll
    for (int tt = 0; tt < 8; ++tt) {
      const int t = hh * 8 + tt;
      f32x2 a = y[t][0];
      f32x2 bb = y[t][1];
      float za = __builtin_amdgcn_rcpf(a.x * a.y);
      float zb = __builtin_amdgcn_rcpf(bb.x * bb.y);
      f32x2 ra = za * __builtin_shufflevector(a, a, 1, 0);
      f32x2 rb = zb * __builtin_shufflevector(bb, bb, 1, 0);
      f32x2 wa = ra * ra;
      f32x2 wb = rb * rb;
      const int c2 = ((w + WV * t) * 16 + l16) * 2 - hh * 2048;  // local col byte
#pragma unroll
      for (int j = 0; j < 4; ++j) {
        const int r = quad * 4 + j;
        const float wv = (j == 0) ? wa.x : (j == 1) ? wa.y
                       : (j == 2) ? wb.x : wb.y;
        *(__bf16*)(slab + r * 2048 + (c2 ^ ((r & 7) << 4))) = (__bf16)wv;
      }
    }
    __syncthreads();

    // ---- phase 5 (half): p = hh*4 .. hh*4+3 ----
#pragma unroll
    for (int pp = 0; pp < 4; ++pp) {
      const int p = hh * 4 + pp;
      const size_t vo = ((size_t)(p * 8 + w) * 4) * 512 + lane * 8;
      bf16x8 bhv0 = *(const bf16x8*)(vpbh + vo);
      bf16x8 bhv1 = *(const bf16x8*)(vpbh + vo + 512);
      bf16x8 bhv2 = *(const bf16x8*)(vpbh + vo + 1024);
      bf16x8 bhv3 = *(const bf16x8*)(vpbh + vo + 1536);
      bf16x8 blv0 = *(const bf16x8*)(vpbl + vo);
      bf16x8 blv1 = *(const bf16x8*)(vpbl + vo + 512);
      bf16x8 blv2 = *(const bf16x8*)(vpbl + vo + 1024);
      bf16x8 blv3 = *(const bf16x8*)(vpbl + vo + 1536);

      // A-fragment keys must match the V-pack's k ordering:
      //   k = quad*8 + j  ->  key = (16p + 8*(quad>>1) + w)*16 + (quad&1)*8 + j
      // (quads 0-1: kt = 16p+w; quads 2-3: kt = 16p+8+w), row = l16.
      const int c2 =
          ((16 * p + 8 * (quad >> 1) + w) * 16 + (quad & 1) * 8) * 2 - hh * 2048;
      bf16x8 aw =
          *(const bf16x8*)(slab + l16 * 2048 + (c2 ^ ((l16 & 7) << 4)));

      oacc[0] = __builtin_amdgcn_mfma_f32_16x16x32_bf16(aw, bhv0, oacc[0], 0, 0, 0);
      oacc[1] = __builtin_amdgcn_mfma_f32_16x16x32_bf16(aw, bhv1, oacc[1], 0, 0, 0);
      oacc[2] = __builtin_amdgcn_mfma_f32_16x16x32_bf16(aw, bhv2, oacc[2], 0, 0, 0);
      oacc[3] = __builtin_amdgcn_mfma_f32_16x16x32_bf16(aw, bhv3, oacc[3], 0, 0, 0);
      oacc[0] = __builtin_amdgcn_mfma_f32_16x16x32_bf16(aw, blv0, oacc[0], 0, 0, 0);
      oacc[1] = __builtin_amdgcn_mfma_f32_16x16x32_bf16(aw, blv1, oacc[1], 0, 0, 0);
      oacc[2] = __builtin_amdgcn_mfma_f32_16x16x32_bf16(aw, blv2, oacc[2], 0, 0, 0);
      oacc[3] = __builtin_amdgcn_mfma_f32_16x16x32_bf16(aw, blv3, oacc[3], 0, 0, 0);
      // Pressure fence: keep only this p's V-loads in flight.
      asm volatile("" ::: "memory");
    }
  }

  // ---- phase 6: reduce partials across waves, write global ----
  __syncthreads();   // all slab reads complete before overlaying ex
#pragma unroll
  for (int n = 0; n < 4; ++n)
#pragma unroll
    for (int r = 0; r < 4; ++r)
      sh.ex[w][quad * 4 + r][n * 16 + l16] = oacc[n][r];
  __syncthreads();
  {
    const int row = 2 * w + (lane >> 5);
    const int d = lane & 31;
    float v0 = 0.f, v1 = 0.f;
#pragma unroll
    for (int i = 0; i < WV; ++i) {
      v0 += sh.ex[i][row][d];
      v1 += sh.ex[i][row][d + 32];
    }
    const int off = ((b * NL + qbase + row) * NH + h) * ND + d;
    outg[off] = v0;
    outg[off + 32] = v1;
  }
}

extern "C" void kernel_launch(void* const* d_in, const int* in_sizes, int n_in,
                              void* d_out, int out_size, void* d_ws, size_t ws_size,
                              hipStream_t stream) {
  const float* q = (const float*)d_in[0];
  const float* k = (const float*)d_in[1];
  const float* v = (const float*)d_in[2];

  const size_t plane = (size_t)NB * NH * ND * NL;  // 3.15M elems, 6.29MB/plane
  __bf16* kp_hi = (__bf16*)d_ws;
  __bf16* kp_lo = kp_hi + plane;
  __bf16* vp_hi = kp_lo + plane;
  __bf16* vp_lo = vp_hi + plane;

  prep<<<NB * 128 * 3 * 2, 256, 0, stream>>>(k, v, kp_hi, kp_lo, vp_hi, vp_lo);

  attn_poly<<<NB * NH * (NL / 16), 512, 0, stream>>>(
      q, kp_hi, kp_lo, vp_hi, vp_lo, (float*)d_out);
}

// Round 10
// 261.280 us; speedup vs baseline: 1.0025x; 1.0025x over previous
//
#include <hip/hip_runtime.h>
#include <hip/hip_bf16.h>

#define NB 2
#define NL 2048
#define NH 12
#define ND 64
#define NEWTON 6
#define WV 8            // waves per block (attn)
#define TPW 16          // key-tiles per wave = 128/WV

typedef __bf16 bf16x8 __attribute__((ext_vector_type(8)));
typedef float f32x4 __attribute__((ext_vector_type(4)));
typedef float f32x2 __attribute__((ext_vector_type(2)));

// DPP row_ror reductions within each 16-lane row.
#define ROR_ADD(v, n)                                                         \
  (v) += __int_as_float(__builtin_amdgcn_update_dpp(                          \
      0, __float_as_int(v), 0x120 + (n), 0xF, 0xF, true))
#define ROR_MAX(v, n)                                                         \
  (v) = fmaxf((v), __int_as_float(__builtin_amdgcn_update_dpp(                \
                  0, __float_as_int(v), 0x120 + (n), 0xF, 0xF, true)))

// Zero-instruction register-class pin: constrains the live range of x to the
// ArchVGPR class ("v") without emitting any instruction.
#define PIN_V(x) asm("" : "+v"(x))

__device__ __forceinline__ void split_bf16(float f, __bf16& hi, __bf16& lo) {
  __bf16 h = (__bf16)f;
  hi = h;
  lo = (__bf16)(f - (float)h);
}

// ---- prep: block = (b, kt16, head-group of 4) x {K,V}. 1536 blocks, 256 thr,
// 16.6 KB LDS. K-blocks and V-blocks are independent for 2x parallelism.
__global__ __launch_bounds__(256) void prep(
    const float* __restrict__ kg, const float* __restrict__ vg,
    __bf16* __restrict__ kp_hi, __bf16* __restrict__ kp_lo,
    __bf16* __restrict__ vp_hi, __bf16* __restrict__ vp_lo) {
  __shared__ __align__(16) float kv[16][260];  // [key][4 heads x 64 d]
  const int blk = blockIdx.x;
  const int isV = blk >= NB * 128 * 3;
  const int bk = isV ? blk - NB * 128 * 3 : blk;
  const int hg = bk % 3;
  const int kt = (bk / 3) & 127;
  const int b = bk / 384;
  const int t = threadIdx.x;
  const int w = t >> 6;           // wave 0..3 == local head
  const int lane = t & 63;
  const int quad = lane >> 4;
  const int l16 = lane & 15;

  const float* __restrict__ src = isV ? vg : kg;
#pragma unroll
  for (int i = 0; i < 4; ++i) {
    const int f = i * 1024 + t * 4;
    const int key = f >> 8;
    const int rem = f & 255;
    const size_t s =
        (size_t)(b * NL + kt * 16 + key) * (NH * ND) + hg * 256 + rem;
    *(f32x4*)(&kv[key][rem]) = *(const f32x4*)(src + s);
  }
  __syncthreads();

  const int h = hg * 4 + w;

  if (!isV) {
    // ---- K pack ----
    const float* p = &kv[l16][w * 64 + quad * 8];
    f32x4 a0 = *(const f32x4*)(p);
    f32x4 a1 = *(const f32x4*)(p + 4);
    f32x4 a2 = *(const f32x4*)(p + 32);
    f32x4 a3 = *(const f32x4*)(p + 36);
    bf16x8 h0, l0, h1, l1;
#pragma unroll
    for (int j = 0; j < 4; ++j) {
      __bf16 hb, lb;
      split_bf16(a0[j], hb, lb); h0[j] = hb;     l0[j] = lb;
      split_bf16(a1[j], hb, lb); h0[4 + j] = hb; l0[4 + j] = lb;
      split_bf16(a2[j], hb, lb); h1[j] = hb;     l1[j] = lb;
      split_bf16(a3[j], hb, lb); h1[4 + j] = hb; l1[4 + j] = lb;
    }
    const size_t basek =
        ((size_t)((b * NH + h) * 128 + kt) * 2) * 512 + lane * 8;
    *(bf16x8*)(kp_hi + basek) = h0;
    *(bf16x8*)(kp_lo + basek) = l0;
    *(bf16x8*)(kp_hi + basek + 512) = h1;
    *(bf16x8*)(kp_lo + basek + 512) = l1;
  } else {
    // ---- V pack ----
    const int halfsel = (kt >> 3) & 1;
    const int pi = (kt >> 4) * 8 + (kt & 7);
    const int q2 = quad & 1;
    const int nhalf = quad >> 1;
    const int qdst = 2 * halfsel + q2;
#pragma unroll
    for (int nn = 0; nn < 2; ++nn) {
      const int n = nhalf * 2 + nn;
      bf16x8 hv, lv;
#pragma unroll
      for (int j = 0; j < 8; ++j) {
        __bf16 hb, lb;
        split_bf16(kv[q2 * 8 + j][w * 64 + n * 16 + l16], hb, lb);
        hv[j] = hb;
        lv[j] = lb;
      }
      const size_t off =
          ((((size_t)(b * NH + h) * 64 + pi) * 4 + n) * 64 + qdst * 16 + l16) * 8;
      *(bf16x8*)(vp_hi + off) = hv;
      *(bf16x8*)(vp_lo + off) = lv;
    }
  }
}

// ---------------- main fused attention-poly kernel ----------------
// Register-class note: the MFMA intrinsics are selected in AGPR form, so any
// value born as an MFMA accumulator (y = scores) tends to live in the acc
// class, and every VALU use pays a v_accvgpr shuttle (~1400 insts/thread
// across 6 Newton iters). Fix: pin every GENERATION of y to the ArchVGPR
// class with a zero-instruction empty-asm "+v" constraint (PIN_V). The only
// remaining acc->v traffic is the one-time copy after phase 1.
// Arch demand ~64(y)+working ≈ 115 fits the (512,4) budget of 128, no spill
// (spill canary: WRITE_SIZE).
// History: (512,6) -> cap 85, y spilled, 594MB scratch (round 5);
// (512,2) budget 256 did NOT move the split (round 7) -> isel, not budget.
__launch_bounds__(512, 4)
__global__ void attn_poly(const float* __restrict__ qg,
                          const __bf16* __restrict__ kp_hi,
                          const __bf16* __restrict__ kp_lo,
                          const __bf16* __restrict__ vp_hi,
                          const __bf16* __restrict__ vp_lo,
                          float* __restrict__ outg) {
  // Half-keyspace weight slab W[16 rows][1024 keys] bf16, XOR-swizzled
  // (byte ^= (row&7)<<4). Phases 4/5 run twice (keys 0-1023, 1024-2047).
  // 35.5 KB total LDS; overlaid with the phase-6 partial slab.
  __shared__ __align__(16) union ShMem {
    __bf16 wslab[16][1024];      // 32 KB, phases 4-5 (one key-half)
    float ex[WV][16][68];        // 34.8 KB, phase 6
  } sh;
  __shared__ float redmax[WV][17];
  __shared__ float redn[NEWTON][16][2];   // per-iteration atomic sum buffers

  const int tid = threadIdx.x;
  const int w = tid >> 6;
  const int lane = tid & 63;
  const int quad = lane >> 4;
  const int l16 = lane & 15;

  // XCD-aware swizzle: blocks dispatch round-robin over 8 XCDs (blk&7).
  // Give each XCD 3 complete bh groups (24 bh / 8 XCD) so the concurrent
  // block window on an XCD stays within one bh -> K/V (2MB) L2-resident.
  // Bijective: 3072 = 8 * 384, 384 = 3 * 128.
  const int blk = blockIdx.x;
  const int xcd = blk & 7;
  const int slot = blk >> 3;           // 0..383 within this XCD
  const int bh = xcd * 3 + (slot >> 7);
  const int qt = slot & 127;
  const int h = bh % NH;
  const int b = bh / NH;
  const int qbase = qt * 16;

  // ---- Q fragments: fp32 * 0.125 -> bf16 hi/lo ----
  bf16x8 qhi0, qlo0, qhi1, qlo1;
  {
    const float* qp = qg + ((b * NL + qbase + l16) * NH + h) * ND + quad * 8;
    f32x4 a0 = *(const f32x4*)(qp);
    f32x4 a1 = *(const f32x4*)(qp + 4);
    f32x4 a2 = *(const f32x4*)(qp + 32);
    f32x4 a3 = *(const f32x4*)(qp + 36);
#pragma unroll
    for (int j = 0; j < 4; ++j) {
      __bf16 hb, lb;
      split_bf16(a0[j] * 0.125f, hb, lb); qhi0[j] = hb;     qlo0[j] = lb;
      split_bf16(a1[j] * 0.125f, hb, lb); qhi0[4 + j] = hb; qlo0[4 + j] = lb;
      split_bf16(a2[j] * 0.125f, hb, lb); qhi1[j] = hb;     qlo1[j] = lb;
      split_bf16(a3[j] * 0.125f, hb, lb); qhi1[4 + j] = hb; qlo1[4 + j] = lb;
    }
  }

  // ---- phase 1: S = (Q/8) Kt ; y[t][j] = rows (quad*4+2j, +2j+1), col l16 ----
  // y holds raw scores here (acc class); phase 2 converts to y = negc0 - s
  // and pins the result into arch VGPRs.
  f32x2 y[TPW][2];
  {
    const __bf16* kbh = kp_hi + (size_t)bh * 131072;
    const __bf16* kbl = kp_lo + (size_t)bh * 131072;
#pragma unroll
    for (int t = 0; t < TPW; ++t) {
      const int ktile = w + WV * t;
      const size_t o = (size_t)ktile * 1024 + lane * 8;
      bf16x8 khi0 = *(const bf16x8*)(kbh + o);
      bf16x8 khi1 = *(const bf16x8*)(kbh + o + 512);
      bf16x8 klo0 = *(const bf16x8*)(kbl + o);
      bf16x8 klo1 = *(const bf16x8*)(kbl + o + 512);
      f32x4 acc = {0.f, 0.f, 0.f, 0.f};
      acc = __builtin_amdgcn_mfma_f32_16x16x32_bf16(qhi0, khi0, acc, 0, 0, 0);
      acc = __builtin_amdgcn_mfma_f32_16x16x32_bf16(qhi1, khi1, acc, 0, 0, 0);
      acc = __builtin_amdgcn_mfma_f32_16x16x32_bf16(qhi0, klo0, acc, 0, 0, 0);
      acc = __builtin_amdgcn_mfma_f32_16x16x32_bf16(qhi1, klo1, acc, 0, 0, 0);
      acc = __builtin_amdgcn_mfma_f32_16x16x32_bf16(qlo0, khi0, acc, 0, 0, 0);
      acc = __builtin_amdgcn_mfma_f32_16x16x32_bf16(qlo1, khi1, acc, 0, 0, 0);
      y[t][0] = __builtin_shufflevector(acc, acc, 0, 1);
      y[t][1] = __builtin_shufflevector(acc, acc, 2, 3);
    }
  }

  // ---- phase 2: row max -> negc[j] = -c0 pairs (= max + 1); y := negc - s ----
  {
    f32x2 mx2[2] = {y[0][0], y[0][1]};
#pragma unroll
    for (int t = 1; t < TPW; ++t) {
#pragma unroll
      for (int j = 0; j < 2; ++j) {
        mx2[j].x = fmaxf(mx2[j].x, y[t][j].x);
        mx2[j].y = fmaxf(mx2[j].y, y[t][j].y);
      }
    }
#pragma unroll
    for (int j = 0; j < 2; ++j) {
      ROR_MAX(mx2[j].x, 8); ROR_MAX(mx2[j].x, 4); ROR_MAX(mx2[j].x, 2); ROR_MAX(mx2[j].x, 1);
      ROR_MAX(mx2[j].y, 8); ROR_MAX(mx2[j].y, 4); ROR_MAX(mx2[j].y, 2); ROR_MAX(mx2[j].y, 1);
    }
    if (l16 < 4) {
      float v = (l16 == 0) ? mx2[0].x : (l16 == 1) ? mx2[0].y
              : (l16 == 2) ? mx2[1].x : mx2[1].y;
      redmax[w][quad * 4 + l16] = v;
    }
    // zero the Newton atomic buffers under the same barrier
    if (tid < NEWTON * 16 * 2) ((float*)redn)[tid] = 0.f;
    __syncthreads();
    f32x2 negc[2];
#pragma unroll
    for (int r = 0; r < 4; ++r) {
      float m = redmax[l16 & 7][quad * 4 + r];
      ROR_MAX(m, 4); ROR_MAX(m, 2); ROR_MAX(m, 1);
      ((float*)negc)[r] = m + 1.0f;            // -c0 = max + 1
    }
    // convert scores -> y0 = negc0 - s, pinned into arch VGPRs.
#pragma unroll
    for (int t = 0; t < TPW; ++t) {
#pragma unroll
      for (int j = 0; j < 2; ++j) {
        y[t][j] = negc[j] - y[t][j];
        PIN_V(y[t][j]);
      }
    }
  }

  // ---- phase 3: Newton x6 on c (packed-f32 inner loop; cross-wave via ds_add) ----
  for (int it = 0; it < NEWTON; ++it) {
    f32x2 ps2[2] = {{0.f, 0.f}, {0.f, 0.f}};
    f32x2 psd2[2] = {{0.f, 0.f}, {0.f, 0.f}};
#pragma unroll
    for (int t = 0; t < TPW; ++t) {
#pragma unroll
      for (int j = 0; j < 2; ++j) {
        f32x2 v = y[t][j];                     // y >= 1 along Newton path
        float z = __builtin_amdgcn_rcpf(v.x * v.y);
        f32x2 r1 = z * __builtin_shufflevector(v, v, 1, 0);  // (1/y.x, 1/y.y)
        f32x2 r2;
        asm("v_pk_mul_f32 %0, %1, %1" : "=v"(r2) : "v"(r1));
        asm("v_pk_add_f32 %0, %0, %1" : "+v"(ps2[j]) : "v"(r2));
        asm("v_pk_fma_f32 %0, %1, %2, %0" : "+v"(psd2[j]) : "v"(r2), "v"(r1));
      }
    }
#pragma unroll
    for (int j = 0; j < 2; ++j) {
      ROR_ADD(ps2[j].x, 8);  ROR_ADD(ps2[j].x, 4);  ROR_ADD(ps2[j].x, 2);  ROR_ADD(ps2[j].x, 1);
      ROR_ADD(ps2[j].y, 8);  ROR_ADD(ps2[j].y, 4);  ROR_ADD(ps2[j].y, 2);  ROR_ADD(ps2[j].y, 1);
      ROR_ADD(psd2[j].x, 8); ROR_ADD(psd2[j].x, 4); ROR_ADD(psd2[j].x, 2); ROR_ADD(psd2[j].x, 1);
      ROR_ADD(psd2[j].y, 8); ROR_ADD(psd2[j].y, 4); ROR_ADD(psd2[j].y, 2); ROR_ADD(psd2[j].y, 1);
    }
    if (l16 < 4) {
      float a = (l16 == 0) ? ps2[0].x : (l16 == 1) ? ps2[0].y
              : (l16 == 2) ? ps2[1].x : ps2[1].y;
      float d = (l16 == 0) ? psd2[0].x : (l16 == 1) ? psd2[0].y
              : (l16 == 2) ? psd2[1].x : psd2[1].y;
      atomicAdd(&redn[it][quad * 4 + l16][0], a);
      atomicAdd(&redn[it][quad * 4 + l16][1], d);
    }
    __syncthreads();
    f32x2 dd[2];
#pragma unroll
    for (int r = 0; r < 4; ++r) {
      const f32x2 v = *(const f32x2*)(&redn[it][quad * 4 + r][0]);
      ((float*)dd)[r] =
          (v.x - 1.0f) * __builtin_amdgcn_rcpf(2.0f * v.y + 1e-8f);
    }
    // y += dd; re-pin each regeneration so y stays in arch VGPRs.
#pragma unroll
    for (int t = 0; t < TPW; ++t) {
      y[t][0] += dd[0];
      PIN_V(y[t][0]);
      y[t][1] += dd[1];
      PIN_V(y[t][1]);
    }
  }

  // ---- phases 4+5, two key-halves: materialize half the weights into the
  // 32KB swizzled slab, then consume it with V-MFMAs; repeat for the other
  // half. Tiles t = hh*8 .. hh*8+7 cover keys [hh*1024, hh*1024+1024).
  f32x4 oacc[4];
#pragma unroll
  for (int n = 0; n < 4; ++n) oacc[n] = (f32x4){0.f, 0.f, 0.f, 0.f};
  const __bf16* vpbh = vp_hi + (size_t)bh * 131072;
  const __bf16* vpbl = vp_lo + (size_t)bh * 131072;
  char* slab = (char*)&sh.wslab[0][0];

#pragma unroll
  for (int hh = 0; hh < 2; ++hh) {
    if (hh) __syncthreads();   // half-A reads complete before overwrite

    // ---- phase 4 (half): weights for tiles hh*8 .. hh*8+7 ----
#pragma unroll
    for (int tt = 0; tt < 8; ++tt) {
      const int t = hh * 8 + tt;
      f32x2 a = y[t][0];
      f32x2 bb = y[t][1];
      float za = __builtin_amdgcn_rcpf(a.x * a.y);
      float zb = __builtin_amdgcn_rcpf(bb.x * bb.y);
      f32x2 ra = za * __builtin_shufflevector(a, a, 1, 0);
      f32x2 rb = zb * __builtin_shufflevector(bb, bb, 1, 0);
      f32x2 wa = ra * ra;
      f32x2 wb = rb * rb;
      const int c2 = ((w + WV * t) * 16 + l16) * 2 - hh * 2048;  // local col byte
#pragma unroll
      for (int j = 0; j < 4; ++j) {
        const int r = quad * 4 + j;
        const float wv = (j == 0) ? wa.x : (j == 1) ? wa.y
                       : (j == 2) ? wb.x : wb.y;
        *(__bf16*)(slab + r * 2048 + (c2 ^ ((r & 7) << 4))) = (__bf16)wv;
      }
    }
    __syncthreads();

    // ---- phase 5 (half): p = hh*4 .. hh*4+3 ----
#pragma unroll
    for (int pp = 0; pp < 4; ++pp) {
      const int p = hh * 4 + pp;
      const size_t vo = ((size_t)(p * 8 + w) * 4) * 512 + lane * 8;
      bf16x8 bhv0 = *(const bf16x8*)(vpbh + vo);
      bf16x8 bhv1 = *(const bf16x8*)(vpbh + vo + 512);
      bf16x8 bhv2 = *(const bf16x8*)(vpbh + vo + 1024);
      bf16x8 bhv3 = *(const bf16x8*)(vpbh + vo + 1536);
      bf16x8 blv0 = *(const bf16x8*)(vpbl + vo);
      bf16x8 blv1 = *(const bf16x8*)(vpbl + vo + 512);
      bf16x8 blv2 = *(const bf16x8*)(vpbl + vo + 1024);
      bf16x8 blv3 = *(const bf16x8*)(vpbl + vo + 1536);

      // A-fragment keys must match the V-pack's k ordering:
      //   k = quad*8 + j  ->  key = (16p + 8*(quad>>1) + w)*16 + (quad&1)*8 + j
      // (quads 0-1: kt = 16p+w; quads 2-3: kt = 16p+8+w), row = l16.
      const int c2 =
          ((16 * p + 8 * (quad >> 1) + w) * 16 + (quad & 1) * 8) * 2 - hh * 2048;
      bf16x8 aw =
          *(const bf16x8*)(slab + l16 * 2048 + (c2 ^ ((l16 & 7) << 4)));

      oacc[0] = __builtin_amdgcn_mfma_f32_16x16x32_bf16(aw, bhv0, oacc[0], 0, 0, 0);
      oacc[1] = __builtin_amdgcn_mfma_f32_16x16x32_bf16(aw, bhv1, oacc[1], 0, 0, 0);
      oacc[2] = __builtin_amdgcn_mfma_f32_16x16x32_bf16(aw, bhv2, oacc[2], 0, 0, 0);
      oacc[3] = __builtin_amdgcn_mfma_f32_16x16x32_bf16(aw, bhv3, oacc[3], 0, 0, 0);
      oacc[0] = __builtin_amdgcn_mfma_f32_16x16x32_bf16(aw, blv0, oacc[0], 0, 0, 0);
      oacc[1] = __builtin_amdgcn_mfma_f32_16x16x32_bf16(aw, blv1, oacc[1], 0, 0, 0);
      oacc[2] = __builtin_amdgcn_mfma_f32_16x16x32_bf16(aw, blv2, oacc[2], 0, 0, 0);
      oacc[3] = __builtin_amdgcn_mfma_f32_16x16x32_bf16(aw, blv3, oacc[3], 0, 0, 0);
    }
  }

  // ---- phase 6: reduce partials across waves, write global ----
  __syncthreads();   // all slab reads complete before overlaying ex
#pragma unroll
  for (int n = 0; n < 4; ++n)
#pragma unroll
    for (int r = 0; r < 4; ++r)
      sh.ex[w][quad * 4 + r][n * 16 + l16] = oacc[n][r];
  __syncthreads();
  {
    const int row = 2 * w + (lane >> 5);
    const int d = lane & 31;
    float v0 = 0.f, v1 = 0.f;
#pragma unroll
    for (int i = 0; i < WV; ++i) {
      v0 += sh.ex[i][row][d];
      v1 += sh.ex[i][row][d + 32];
    }
    const int off = ((b * NL + qbase + row) * NH + h) * ND + d;
    outg[off] = v0;
    outg[off + 32] = v1;
  }
}

extern "C" void kernel_launch(void* const* d_in, const int* in_sizes, int n_in,
                              void* d_out, int out_size, void* d_ws, size_t ws_size,
                              hipStream_t stream) {
  const float* q = (const float*)d_in[0];
  const float* k = (const float*)d_in[1];
  const float* v = (const float*)d_in[2];

  const size_t plane = (size_t)NB * NH * ND * NL;  // 3.15M elems, 6.29MB/plane
  __bf16* kp_hi = (__bf16*)d_ws;
  __bf16* kp_lo = kp_hi + plane;
  __bf16* vp_hi = kp_lo + plane;
  __bf16* vp_lo = vp_hi + plane;

  prep<<<NB * 128 * 3 * 2, 256, 0, stream>>>(k, v, kp_hi, kp_lo, vp_hi, vp_lo);

  attn_poly<<<NB * NH * (NL / 16), 512, 0, stream>>>(
      q, kp_hi, kp_lo, vp_hi, vp_lo, (float*)d_out);
}

// Round 11
// 217.031 us; speedup vs baseline: 1.2069x; 1.2039x over previous
//
#include <hip/hip_runtime.h>
#include <hip/hip_bf16.h>

#define NB 2
#define NL 2048
#define NH 12
#define ND 64
#define NEWTON 6
#define WV 8            // waves per block (attn)
#define TPW 16          // key-tiles per wave = 128/WV

typedef __bf16 bf16x8 __attribute__((ext_vector_type(8)));
typedef float f32x4 __attribute__((ext_vector_type(4)));
typedef float f32x2 __attribute__((ext_vector_type(2)));

// DPP row_ror reductions within each 16-lane row.
#define ROR_ADD(v, n)                                                         \
  (v) += __int_as_float(__builtin_amdgcn_update_dpp(                          \
      0, __float_as_int(v), 0x120 + (n), 0xF, 0xF, true))
#define ROR_MAX(v, n)                                                         \
  (v) = fmaxf((v), __int_as_float(__builtin_amdgcn_update_dpp(                \
                  0, __float_as_int(v), 0x120 + (n), 0xF, 0xF, true)))

// ---- prep: block = (b, kt16, head-group of 4) x {K,V}. 1536 blocks, 256 thr,
// 16.6 KB LDS. Single-bf16 pack (no hi/lo): error analysis shows the final
// y = negc - x ~ 38 makes weight sensitivity to score error ~3.7e-5 — bf16
// operand rounding contributes ~1e-5..5e-4 to the output vs threshold 3.9e-3.
__global__ __launch_bounds__(256) void prep(
    const float* __restrict__ kg, const float* __restrict__ vg,
    __bf16* __restrict__ kp, __bf16* __restrict__ vp) {
  __shared__ __align__(16) float kv[16][260];  // [key][4 heads x 64 d]
  const int blk = blockIdx.x;
  const int isV = blk >= NB * 128 * 3;
  const int bk = isV ? blk - NB * 128 * 3 : blk;
  const int hg = bk % 3;
  const int kt = (bk / 3) & 127;
  const int b = bk / 384;
  const int t = threadIdx.x;
  const int w = t >> 6;           // wave 0..3 == local head
  const int lane = t & 63;
  const int quad = lane >> 4;
  const int l16 = lane & 15;

  const float* __restrict__ src = isV ? vg : kg;
#pragma unroll
  for (int i = 0; i < 4; ++i) {
    const int f = i * 1024 + t * 4;
    const int key = f >> 8;
    const int rem = f & 255;
    const size_t s =
        (size_t)(b * NL + kt * 16 + key) * (NH * ND) + hg * 256 + rem;
    *(f32x4*)(&kv[key][rem]) = *(const f32x4*)(src + s);
  }
  __syncthreads();

  const int h = hg * 4 + w;

  if (!isV) {
    // ---- K pack (single bf16) ----
    const float* p = &kv[l16][w * 64 + quad * 8];
    f32x4 a0 = *(const f32x4*)(p);
    f32x4 a1 = *(const f32x4*)(p + 4);
    f32x4 a2 = *(const f32x4*)(p + 32);
    f32x4 a3 = *(const f32x4*)(p + 36);
    bf16x8 h0, h1;
#pragma unroll
    for (int j = 0; j < 4; ++j) {
      h0[j] = (__bf16)a0[j];
      h0[4 + j] = (__bf16)a1[j];
      h1[j] = (__bf16)a2[j];
      h1[4 + j] = (__bf16)a3[j];
    }
    const size_t basek =
        ((size_t)((b * NH + h) * 128 + kt) * 2) * 512 + lane * 8;
    *(bf16x8*)(kp + basek) = h0;
    *(bf16x8*)(kp + basek + 512) = h1;
  } else {
    // ---- V pack (single bf16) ----
    const int halfsel = (kt >> 3) & 1;
    const int pi = (kt >> 4) * 8 + (kt & 7);
    const int q2 = quad & 1;
    const int nhalf = quad >> 1;
    const int qdst = 2 * halfsel + q2;
#pragma unroll
    for (int nn = 0; nn < 2; ++nn) {
      const int n = nhalf * 2 + nn;
      bf16x8 hv;
#pragma unroll
      for (int j = 0; j < 8; ++j)
        hv[j] = (__bf16)kv[q2 * 8 + j][w * 64 + n * 16 + l16];
      const size_t off =
          ((((size_t)(b * NH + h) * 64 + pi) * 4 + n) * 64 + qdst * 16 + l16) * 8;
      *(bf16x8*)(vp + off) = hv;
    }
  }
}

// ---------------- main fused attention-poly kernel ----------------
// Single-bf16 operands: phase 1 = 2 MFMA/tile (was 6 with hi/lo), phase 5 =
// 4 MFMA+4 loads/p (was 8+8). Newton (the VALU floor, ~60us) unchanged.
// History: AGPR-shuttle theory refuted (r7 budget, r8-r10 pins all null);
// (512,6) spills y (r5) — keep (512,4).
__launch_bounds__(512, 4)
__global__ void attn_poly(const float* __restrict__ qg,
                          const __bf16* __restrict__ kp,
                          const __bf16* __restrict__ vp,
                          float* __restrict__ outg) {
  // Half-keyspace weight slab W[16 rows][1024 keys] bf16, XOR-swizzled
  // (byte ^= (row&7)<<4). Phases 4/5 run twice (keys 0-1023, 1024-2047).
  // 35.5 KB total LDS; overlaid with the phase-6 partial slab.
  __shared__ __align__(16) union ShMem {
    __bf16 wslab[16][1024];      // 32 KB, phases 4-5 (one key-half)
    float ex[WV][16][68];        // 34.8 KB, phase 6
  } sh;
  __shared__ float redmax[WV][17];
  __shared__ float redn[NEWTON][16][2];   // per-iteration atomic sum buffers

  const int tid = threadIdx.x;
  const int w = tid >> 6;
  const int lane = tid & 63;
  const int quad = lane >> 4;
  const int l16 = lane & 15;

  // XCD-aware swizzle: blocks dispatch round-robin over 8 XCDs (blk&7).
  // Each XCD gets 3 complete bh groups so its concurrent block window shares
  // one bh -> K/V L2-resident (FETCH 104MB -> 18.5MB, round 4).
  const int blk = blockIdx.x;
  const int xcd = blk & 7;
  const int slot = blk >> 3;           // 0..383 within this XCD
  const int bh = xcd * 3 + (slot >> 7);
  const int qt = slot & 127;
  const int h = bh % NH;
  const int b = bh / NH;
  const int qbase = qt * 16;

  // ---- Q fragments: fp32 * 0.125 -> bf16 ----
  bf16x8 q0, q1;
  {
    const float* qp = qg + ((b * NL + qbase + l16) * NH + h) * ND + quad * 8;
    f32x4 a0 = *(const f32x4*)(qp);
    f32x4 a1 = *(const f32x4*)(qp + 4);
    f32x4 a2 = *(const f32x4*)(qp + 32);
    f32x4 a3 = *(const f32x4*)(qp + 36);
#pragma unroll
    for (int j = 0; j < 4; ++j) {
      q0[j] = (__bf16)(a0[j] * 0.125f);
      q0[4 + j] = (__bf16)(a1[j] * 0.125f);
      q1[j] = (__bf16)(a2[j] * 0.125f);
      q1[4 + j] = (__bf16)(a3[j] * 0.125f);
    }
  }

  // ---- phase 1: S = (Q/8) Kt ; y[t][j] = rows (quad*4+2j, +2j+1), col l16 ----
  // y holds raw scores here; converted to y = negc0 - s after the max phase,
  // then updated in place by the Newton corrections.
  f32x2 y[TPW][2];
  {
    const __bf16* kb = kp + (size_t)bh * 131072;
#pragma unroll
    for (int t = 0; t < TPW; ++t) {
      const int ktile = w + WV * t;
      const size_t o = (size_t)ktile * 1024 + lane * 8;
      bf16x8 k0 = *(const bf16x8*)(kb + o);
      bf16x8 k1 = *(const bf16x8*)(kb + o + 512);
      f32x4 acc = {0.f, 0.f, 0.f, 0.f};
      acc = __builtin_amdgcn_mfma_f32_16x16x32_bf16(q0, k0, acc, 0, 0, 0);
      acc = __builtin_amdgcn_mfma_f32_16x16x32_bf16(q1, k1, acc, 0, 0, 0);
      y[t][0] = __builtin_shufflevector(acc, acc, 0, 1);
      y[t][1] = __builtin_shufflevector(acc, acc, 2, 3);
    }
  }

  // ---- phase 2: row max -> negc[j] = -c0 pairs (= max + 1); y := negc - s ----
  {
    f32x2 mx2[2] = {y[0][0], y[0][1]};
#pragma unroll
    for (int t = 1; t < TPW; ++t) {
#pragma unroll
      for (int j = 0; j < 2; ++j) {
        mx2[j].x = fmaxf(mx2[j].x, y[t][j].x);
        mx2[j].y = fmaxf(mx2[j].y, y[t][j].y);
      }
    }
#pragma unroll
    for (int j = 0; j < 2; ++j) {
      ROR_MAX(mx2[j].x, 8); ROR_MAX(mx2[j].x, 4); ROR_MAX(mx2[j].x, 2); ROR_MAX(mx2[j].x, 1);
      ROR_MAX(mx2[j].y, 8); ROR_MAX(mx2[j].y, 4); ROR_MAX(mx2[j].y, 2); ROR_MAX(mx2[j].y, 1);
    }
    if (l16 < 4) {
      float v = (l16 == 0) ? mx2[0].x : (l16 == 1) ? mx2[0].y
              : (l16 == 2) ? mx2[1].x : mx2[1].y;
      redmax[w][quad * 4 + l16] = v;
    }
    // zero the Newton atomic buffers under the same barrier
    if (tid < NEWTON * 16 * 2) ((float*)redn)[tid] = 0.f;
    __syncthreads();
    f32x2 negc[2];
#pragma unroll
    for (int r = 0; r < 4; ++r) {
      float m = redmax[l16 & 7][quad * 4 + r];
      ROR_MAX(m, 4); ROR_MAX(m, 2); ROR_MAX(m, 1);
      ((float*)negc)[r] = m + 1.0f;            // -c0 = max + 1
    }
    // convert scores -> y0 = negc0 - s  (in place)
#pragma unroll
    for (int t = 0; t < TPW; ++t) {
      y[t][0] = negc[0] - y[t][0];
      y[t][1] = negc[1] - y[t][1];
    }
  }

  // ---- phase 3: Newton x6 on c (packed-f32 inner loop; cross-wave via ds_add) ----
  for (int it = 0; it < NEWTON; ++it) {
    f32x2 ps2[2] = {{0.f, 0.f}, {0.f, 0.f}};
    f32x2 psd2[2] = {{0.f, 0.f}, {0.f, 0.f}};
#pragma unroll
    for (int t = 0; t < TPW; ++t) {
#pragma unroll
      for (int j = 0; j < 2; ++j) {
        f32x2 v = y[t][j];                     // y >= 1 along Newton path
        float z = __builtin_amdgcn_rcpf(v.x * v.y);
        f32x2 r1 = z * __builtin_shufflevector(v, v, 1, 0);  // (1/y.x, 1/y.y)
        f32x2 r2;
        asm("v_pk_mul_f32 %0, %1, %1" : "=v"(r2) : "v"(r1));
        asm("v_pk_add_f32 %0, %0, %1" : "+v"(ps2[j]) : "v"(r2));
        asm("v_pk_fma_f32 %0, %1, %2, %0" : "+v"(psd2[j]) : "v"(r2), "v"(r1));
      }
    }
#pragma unroll
    for (int j = 0; j < 2; ++j) {
      ROR_ADD(ps2[j].x, 8);  ROR_ADD(ps2[j].x, 4);  ROR_ADD(ps2[j].x, 2);  ROR_ADD(ps2[j].x, 1);
      ROR_ADD(ps2[j].y, 8);  ROR_ADD(ps2[j].y, 4);  ROR_ADD(ps2[j].y, 2);  ROR_ADD(ps2[j].y, 1);
      ROR_ADD(psd2[j].x, 8); ROR_ADD(psd2[j].x, 4); ROR_ADD(psd2[j].x, 2); ROR_ADD(psd2[j].x, 1);
      ROR_ADD(psd2[j].y, 8); ROR_ADD(psd2[j].y, 4); ROR_ADD(psd2[j].y, 2); ROR_ADD(psd2[j].y, 1);
    }
    if (l16 < 4) {
      float a = (l16 == 0) ? ps2[0].x : (l16 == 1) ? ps2[0].y
              : (l16 == 2) ? ps2[1].x : ps2[1].y;
      float d = (l16 == 0) ? psd2[0].x : (l16 == 1) ? psd2[0].y
              : (l16 == 2) ? psd2[1].x : psd2[1].y;
      atomicAdd(&redn[it][quad * 4 + l16][0], a);
      atomicAdd(&redn[it][quad * 4 + l16][1], d);
    }
    __syncthreads();
    f32x2 dd[2];
#pragma unroll
    for (int r = 0; r < 4; ++r) {
      const f32x2 v = *(const f32x2*)(&redn[it][quad * 4 + r][0]);
      ((float*)dd)[r] =
          (v.x - 1.0f) * __builtin_amdgcn_rcpf(2.0f * v.y + 1e-8f);
    }
#pragma unroll
    for (int t = 0; t < TPW; ++t) {
      y[t][0] += dd[0];
      y[t][1] += dd[1];
    }
  }

  // ---- phases 4+5, two key-halves: materialize half the weights into the
  // 32KB swizzled slab, then consume it with V-MFMAs; repeat for the other
  // half. Tiles t = hh*8 .. hh*8+7 cover keys [hh*1024, hh*1024+1024).
  f32x4 oacc[4];
#pragma unroll
  for (int n = 0; n < 4; ++n) oacc[n] = (f32x4){0.f, 0.f, 0.f, 0.f};
  const __bf16* vpb = vp + (size_t)bh * 131072;
  char* slab = (char*)&sh.wslab[0][0];

#pragma unroll
  for (int hh = 0; hh < 2; ++hh) {
    if (hh) __syncthreads();   // half-A reads complete before overwrite

    // ---- phase 4 (half): weights for tiles hh*8 .. hh*8+7 ----
#pragma unroll
    for (int tt = 0; tt < 8; ++tt) {
      const int t = hh * 8 + tt;
      f32x2 a = y[t][0];
      f32x2 bb = y[t][1];
      float za = __builtin_amdgcn_rcpf(a.x * a.y);
      float zb = __builtin_amdgcn_rcpf(bb.x * bb.y);
      f32x2 ra = za * __builtin_shufflevector(a, a, 1, 0);
      f32x2 rb = zb * __builtin_shufflevector(bb, bb, 1, 0);
      f32x2 wa = ra * ra;
      f32x2 wb = rb * rb;
      const int c2 = ((w + WV * t) * 16 + l16) * 2 - hh * 2048;  // local col byte
#pragma unroll
      for (int j = 0; j < 4; ++j) {
        const int r = quad * 4 + j;
        const float wv = (j == 0) ? wa.x : (j == 1) ? wa.y
                       : (j == 2) ? wb.x : wb.y;
        *(__bf16*)(slab + r * 2048 + (c2 ^ ((r & 7) << 4))) = (__bf16)wv;
      }
    }
    __syncthreads();

    // ---- phase 5 (half): p = hh*4 .. hh*4+3 ----
#pragma unroll
    for (int pp = 0; pp < 4; ++pp) {
      const int p = hh * 4 + pp;
      const size_t vo = ((size_t)(p * 8 + w) * 4) * 512 + lane * 8;
      bf16x8 v0 = *(const bf16x8*)(vpb + vo);
      bf16x8 v1 = *(const bf16x8*)(vpb + vo + 512);
      bf16x8 v2 = *(const bf16x8*)(vpb + vo + 1024);
      bf16x8 v3 = *(const bf16x8*)(vpb + vo + 1536);

      // A-fragment keys must match the V-pack's k ordering:
      //   k = quad*8 + j  ->  key = (16p + 8*(quad>>1) + w)*16 + (quad&1)*8 + j
      // (quads 0-1: kt = 16p+w; quads 2-3: kt = 16p+8+w), row = l16.
      const int c2 =
          ((16 * p + 8 * (quad >> 1) + w) * 16 + (quad & 1) * 8) * 2 - hh * 2048;
      bf16x8 aw =
          *(const bf16x8*)(slab + l16 * 2048 + (c2 ^ ((l16 & 7) << 4)));

      oacc[0] = __builtin_amdgcn_mfma_f32_16x16x32_bf16(aw, v0, oacc[0], 0, 0, 0);
      oacc[1] = __builtin_amdgcn_mfma_f32_16x16x32_bf16(aw, v1, oacc[1], 0, 0, 0);
      oacc[2] = __builtin_amdgcn_mfma_f32_16x16x32_bf16(aw, v2, oacc[2], 0, 0, 0);
      oacc[3] = __builtin_amdgcn_mfma_f32_16x16x32_bf16(aw, v3, oacc[3], 0, 0, 0);
    }
  }

  // ---- phase 6: reduce partials across waves, write global ----
  __syncthreads();   // all slab reads complete before overlaying ex
#pragma unroll
  for (int n = 0; n < 4; ++n)
#pragma unroll
    for (int r = 0; r < 4; ++r)
      sh.ex[w][quad * 4 + r][n * 16 + l16] = oacc[n][r];
  __syncthreads();
  {
    const int row = 2 * w + (lane >> 5);
    const int d = lane & 31;
    float v0 = 0.f, v1 = 0.f;
#pragma unroll
    for (int i = 0; i < WV; ++i) {
      v0 += sh.ex[i][row][d];
      v1 += sh.ex[i][row][d + 32];
    }
    const int off = ((b * NL + qbase + row) * NH + h) * ND + d;
    outg[off] = v0;
    outg[off + 32] = v1;
  }
}

extern "C" void kernel_launch(void* const* d_in, const int* in_sizes, int n_in,
                              void* d_out, int out_size, void* d_ws, size_t ws_size,
                              hipStream_t stream) {
  const float* q = (const float*)d_in[0];
  const float* k = (const float*)d_in[1];
  const float* v = (const float*)d_in[2];

  const size_t plane = (size_t)NB * NH * ND * NL;  // 3.15M elems, 6.29MB/plane
  __bf16* kp = (__bf16*)d_ws;
  __bf16* vp = kp + plane;

  prep<<<NB * 128 * 3 * 2, 256, 0, stream>>>(k, v, kp, vp);

  attn_poly<<<NB * NH * (NL / 16), 512, 0, stream>>>(
      q, kp, vp, (float*)d_out);
}

// Round 12
// 211.054 us; speedup vs baseline: 1.2410x; 1.0283x over previous
//
#include <hip/hip_runtime.h>
#include <hip/hip_bf16.h>

#define NB 2
#define NL 2048
#define NH 12
#define ND 64
#define NEWTON 6
#define WV 8            // waves per block (attn)
#define TPW 16          // key-tiles per wave = 128/WV

typedef __bf16 bf16x8 __attribute__((ext_vector_type(8)));
typedef float f32x4 __attribute__((ext_vector_type(4)));
typedef float f32x2 __attribute__((ext_vector_type(2)));

// DPP row_ror reductions within each 16-lane row.
#define ROR_ADD(v, n)                                                         \
  (v) += __int_as_float(__builtin_amdgcn_update_dpp(                          \
      0, __float_as_int(v), 0x120 + (n), 0xF, 0xF, true))
#define ROR_MAX(v, n)                                                         \
  (v) = fmaxf((v), __int_as_float(__builtin_amdgcn_update_dpp(                \
                  0, __float_as_int(v), 0x120 + (n), 0xF, 0xF, true)))

// ---- prep: block = (b, kt16, head-group of 4) x {K,V}. 1536 blocks, 256 thr,
// 16.6 KB LDS. Single-bf16 pack (no hi/lo): error analysis shows the final
// y = negc - x ~ 38 makes weight sensitivity to score error ~3.7e-5 — bf16
// operand rounding stays below the output quantization floor (absmax pinned
// at 2^-10 across rounds, threshold 3.9e-3).
__global__ __launch_bounds__(256) void prep(
    const float* __restrict__ kg, const float* __restrict__ vg,
    __bf16* __restrict__ kp, __bf16* __restrict__ vp) {
  __shared__ __align__(16) float kv[16][260];  // [key][4 heads x 64 d]
  const int blk = blockIdx.x;
  const int isV = blk >= NB * 128 * 3;
  const int bk = isV ? blk - NB * 128 * 3 : blk;
  const int hg = bk % 3;
  const int kt = (bk / 3) & 127;
  const int b = bk / 384;
  const int t = threadIdx.x;
  const int w = t >> 6;           // wave 0..3 == local head
  const int lane = t & 63;
  const int quad = lane >> 4;
  const int l16 = lane & 15;

  const float* __restrict__ src = isV ? vg : kg;
#pragma unroll
  for (int i = 0; i < 4; ++i) {
    const int f = i * 1024 + t * 4;
    const int key = f >> 8;
    const int rem = f & 255;
    const size_t s =
        (size_t)(b * NL + kt * 16 + key) * (NH * ND) + hg * 256 + rem;
    *(f32x4*)(&kv[key][rem]) = *(const f32x4*)(src + s);
  }
  __syncthreads();

  const int h = hg * 4 + w;

  if (!isV) {
    // ---- K pack (single bf16) ----
    const float* p = &kv[l16][w * 64 + quad * 8];
    f32x4 a0 = *(const f32x4*)(p);
    f32x4 a1 = *(const f32x4*)(p + 4);
    f32x4 a2 = *(const f32x4*)(p + 32);
    f32x4 a3 = *(const f32x4*)(p + 36);
    bf16x8 h0, h1;
#pragma unroll
    for (int j = 0; j < 4; ++j) {
      h0[j] = (__bf16)a0[j];
      h0[4 + j] = (__bf16)a1[j];
      h1[j] = (__bf16)a2[j];
      h1[4 + j] = (__bf16)a3[j];
    }
    const size_t basek =
        ((size_t)((b * NH + h) * 128 + kt) * 2) * 512 + lane * 8;
    *(bf16x8*)(kp + basek) = h0;
    *(bf16x8*)(kp + basek + 512) = h1;
  } else {
    // ---- V pack (single bf16) ----
    const int halfsel = (kt >> 3) & 1;
    const int pi = (kt >> 4) * 8 + (kt & 7);
    const int q2 = quad & 1;
    const int nhalf = quad >> 1;
    const int qdst = 2 * halfsel + q2;
#pragma unroll
    for (int nn = 0; nn < 2; ++nn) {
      const int n = nhalf * 2 + nn;
      bf16x8 hv;
#pragma unroll
      for (int j = 0; j < 8; ++j)
        hv[j] = (__bf16)kv[q2 * 8 + j][w * 64 + n * 16 + l16];
      const size_t off =
          ((((size_t)(b * NH + h) * 64 + pi) * 4 + n) * 64 + qdst * 16 + l16) * 8;
      *(bf16x8*)(vp + off) = hv;
    }
  }
}

// ---------------- main fused attention-poly kernel ----------------
// Single-bf16 operands (r11). Phases 4+5 merged via per-wave double-buffered
// weight slabs (r0's proven pattern): each wave's PV tiles (pi=8p+w <->
// score tiles 2p,2p+1 of wave w) consume only weights that wave computes, so
// the weight handoff needs NO block barriers — just an lgkmcnt wait. Next-p
// weights are written between the aw read and the MFMAs so their latency
// hides under the V loads/MFMAs. Barriers: 12 -> 9.
// History: AGPR-shuttle theory refuted (r7 budget, r8-r10 pins all null);
// (512,6) spills y (r5) — keep (512,4). Occupancy pinned at 2 blocks/CU by
// y[16][2] (64 f32) + working set in the (103,128] reg bracket.
__launch_bounds__(512, 4)
__global__ void attn_poly(const float* __restrict__ qg,
                          const __bf16* __restrict__ kp,
                          const __bf16* __restrict__ vp,
                          float* __restrict__ outg) {
  // Per-wave union: phase-5 weight slab overlays phase-6 partial slab.
  // Each wave only touches its own pw[w] until the phase-6 barrier, and the
  // last ws read (p=7) precedes the first ex write in program order (DS ops
  // are in-order per wave), so the overlay is race-free.
  struct PW {
    union {
      float ex[16][68];          // phase 6 partials (4352 B)
      __bf16 ws[2][16][40];      // phase 5 dbuf weight slabs (2560 B)
    };
  };
  __shared__ __align__(16) PW pw[WV];
  __shared__ float redmax[WV][17];
  __shared__ float redn[NEWTON][16][2];   // per-iteration atomic sum buffers

  const int tid = threadIdx.x;
  const int w = tid >> 6;
  const int lane = tid & 63;
  const int quad = lane >> 4;
  const int l16 = lane & 15;

  // XCD-aware swizzle: blocks dispatch round-robin over 8 XCDs (blk&7).
  // Each XCD gets 3 complete bh groups so its concurrent block window shares
  // one bh -> K/V L2-resident (FETCH 104MB -> 18.5MB, round 4).
  const int blk = blockIdx.x;
  const int xcd = blk & 7;
  const int slot = blk >> 3;           // 0..383 within this XCD
  const int bh = xcd * 3 + (slot >> 7);
  const int qt = slot & 127;
  const int h = bh % NH;
  const int b = bh / NH;
  const int qbase = qt * 16;

  // ---- Q fragments: fp32 * 0.125 -> bf16 ----
  bf16x8 q0, q1;
  {
    const float* qp = qg + ((b * NL + qbase + l16) * NH + h) * ND + quad * 8;
    f32x4 a0 = *(const f32x4*)(qp);
    f32x4 a1 = *(const f32x4*)(qp + 4);
    f32x4 a2 = *(const f32x4*)(qp + 32);
    f32x4 a3 = *(const f32x4*)(qp + 36);
#pragma unroll
    for (int j = 0; j < 4; ++j) {
      q0[j] = (__bf16)(a0[j] * 0.125f);
      q0[4 + j] = (__bf16)(a1[j] * 0.125f);
      q1[j] = (__bf16)(a2[j] * 0.125f);
      q1[4 + j] = (__bf16)(a3[j] * 0.125f);
    }
  }

  // ---- phase 1: S = (Q/8) Kt ; y[t][j] = rows (quad*4+2j, +2j+1), col l16 ----
  // y holds raw scores here; converted to y = negc0 - s after the max phase,
  // then updated in place by the Newton corrections.
  f32x2 y[TPW][2];
  {
    const __bf16* kb = kp + (size_t)bh * 131072;
#pragma unroll
    for (int t = 0; t < TPW; ++t) {
      const int ktile = w + WV * t;
      const size_t o = (size_t)ktile * 1024 + lane * 8;
      bf16x8 k0 = *(const bf16x8*)(kb + o);
      bf16x8 k1 = *(const bf16x8*)(kb + o + 512);
      f32x4 acc = {0.f, 0.f, 0.f, 0.f};
      acc = __builtin_amdgcn_mfma_f32_16x16x32_bf16(q0, k0, acc, 0, 0, 0);
      acc = __builtin_amdgcn_mfma_f32_16x16x32_bf16(q1, k1, acc, 0, 0, 0);
      y[t][0] = __builtin_shufflevector(acc, acc, 0, 1);
      y[t][1] = __builtin_shufflevector(acc, acc, 2, 3);
    }
  }

  // ---- phase 2: row max -> negc[j] = -c0 pairs (= max + 1); y := negc - s ----
  {
    f32x2 mx2[2] = {y[0][0], y[0][1]};
#pragma unroll
    for (int t = 1; t < TPW; ++t) {
#pragma unroll
      for (int j = 0; j < 2; ++j) {
        mx2[j].x = fmaxf(mx2[j].x, y[t][j].x);
        mx2[j].y = fmaxf(mx2[j].y, y[t][j].y);
      }
    }
#pragma unroll
    for (int j = 0; j < 2; ++j) {
      ROR_MAX(mx2[j].x, 8); ROR_MAX(mx2[j].x, 4); ROR_MAX(mx2[j].x, 2); ROR_MAX(mx2[j].x, 1);
      ROR_MAX(mx2[j].y, 8); ROR_MAX(mx2[j].y, 4); ROR_MAX(mx2[j].y, 2); ROR_MAX(mx2[j].y, 1);
    }
    if (l16 < 4) {
      float v = (l16 == 0) ? mx2[0].x : (l16 == 1) ? mx2[0].y
              : (l16 == 2) ? mx2[1].x : mx2[1].y;
      redmax[w][quad * 4 + l16] = v;
    }
    // zero the Newton atomic buffers under the same barrier
    if (tid < NEWTON * 16 * 2) ((float*)redn)[tid] = 0.f;
    __syncthreads();
    f32x2 negc[2];
#pragma unroll
    for (int r = 0; r < 4; ++r) {
      float m = redmax[l16 & 7][quad * 4 + r];
      ROR_MAX(m, 4); ROR_MAX(m, 2); ROR_MAX(m, 1);
      ((float*)negc)[r] = m + 1.0f;            // -c0 = max + 1
    }
    // convert scores -> y0 = negc0 - s  (in place)
#pragma unroll
    for (int t = 0; t < TPW; ++t) {
      y[t][0] = negc[0] - y[t][0];
      y[t][1] = negc[1] - y[t][1];
    }
  }

  // ---- phase 3: Newton x6 on c (packed-f32 inner loop; cross-wave via ds_add) ----
  for (int it = 0; it < NEWTON; ++it) {
    f32x2 ps2[2] = {{0.f, 0.f}, {0.f, 0.f}};
    f32x2 psd2[2] = {{0.f, 0.f}, {0.f, 0.f}};
#pragma unroll
    for (int t = 0; t < TPW; ++t) {
#pragma unroll
      for (int j = 0; j < 2; ++j) {
        f32x2 v = y[t][j];                     // y >= 1 along Newton path
        float z = __builtin_amdgcn_rcpf(v.x * v.y);
        f32x2 r1 = z * __builtin_shufflevector(v, v, 1, 0);  // (1/y.x, 1/y.y)
        f32x2 r2;
        asm("v_pk_mul_f32 %0, %1, %1" : "=v"(r2) : "v"(r1));
        asm("v_pk_add_f32 %0, %0, %1" : "+v"(ps2[j]) : "v"(r2));
        asm("v_pk_fma_f32 %0, %1, %2, %0" : "+v"(psd2[j]) : "v"(r2), "v"(r1));
      }
    }
#pragma unroll
    for (int j = 0; j < 2; ++j) {
      ROR_ADD(ps2[j].x, 8);  ROR_ADD(ps2[j].x, 4);  ROR_ADD(ps2[j].x, 2);  ROR_ADD(ps2[j].x, 1);
      ROR_ADD(ps2[j].y, 8);  ROR_ADD(ps2[j].y, 4);  ROR_ADD(ps2[j].y, 2);  ROR_ADD(ps2[j].y, 1);
      ROR_ADD(psd2[j].x, 8); ROR_ADD(psd2[j].x, 4); ROR_ADD(psd2[j].x, 2); ROR_ADD(psd2[j].x, 1);
      ROR_ADD(psd2[j].y, 8); ROR_ADD(psd2[j].y, 4); ROR_ADD(psd2[j].y, 2); ROR_ADD(psd2[j].y, 1);
    }
    if (l16 < 4) {
      float a = (l16 == 0) ? ps2[0].x : (l16 == 1) ? ps2[0].y
              : (l16 == 2) ? ps2[1].x : ps2[1].y;
      float d = (l16 == 0) ? psd2[0].x : (l16 == 1) ? psd2[0].y
              : (l16 == 2) ? psd2[1].x : psd2[1].y;
      atomicAdd(&redn[it][quad * 4 + l16][0], a);
      atomicAdd(&redn[it][quad * 4 + l16][1], d);
    }
    __syncthreads();
    f32x2 dd[2];
#pragma unroll
    for (int r = 0; r < 4; ++r) {
      const f32x2 v = *(const f32x2*)(&redn[it][quad * 4 + r][0]);
      ((float*)dd)[r] =
          (v.x - 1.0f) * __builtin_amdgcn_rcpf(2.0f * v.y + 1e-8f);
    }
#pragma unroll
    for (int t = 0; t < TPW; ++t) {
      y[t][0] += dd[0];
      y[t][1] += dd[1];
    }
  }

  // ---- phase 5: O = W * V; per-wave double-buffered bf16 weight slab ----
  // Weights for p-iter's two tiles (t=2p, 2p+1) are written one iteration
  // AHEAD into the alternate buffer, so the single lgkmcnt wait covers a
  // write whose latency was hidden by the previous iteration's MFMAs/loads.
  f32x4 oacc[4];
#pragma unroll
  for (int n = 0; n < 4; ++n) oacc[n] = (f32x4){0.f, 0.f, 0.f, 0.f};
  const __bf16* vpb = vp + (size_t)bh * 131072;

  // prologue: weights for tiles 0,1 -> buf 0
#pragma unroll
  for (int ts = 0; ts < 2; ++ts) {
    f32x2 a = y[ts][0];
    f32x2 bb = y[ts][1];
    float za = __builtin_amdgcn_rcpf(a.x * a.y);
    float zb = __builtin_amdgcn_rcpf(bb.x * bb.y);
    f32x2 ra = za * __builtin_shufflevector(a, a, 1, 0);
    f32x2 rb = zb * __builtin_shufflevector(bb, bb, 1, 0);
    f32x2 wa = ra * ra;
    f32x2 wb = rb * rb;
    pw[w].ws[0][quad * 4 + 0][ts * 16 + l16] = (__bf16)wa.x;
    pw[w].ws[0][quad * 4 + 1][ts * 16 + l16] = (__bf16)wa.y;
    pw[w].ws[0][quad * 4 + 2][ts * 16 + l16] = (__bf16)wb.x;
    pw[w].ws[0][quad * 4 + 3][ts * 16 + l16] = (__bf16)wb.y;
  }

#pragma unroll
  for (int p = 0; p < 8; ++p) {
    const size_t vo = ((size_t)(p * 8 + w) * 4) * 512 + lane * 8;
    // V loads (independent of slab) issue first
    bf16x8 v0 = *(const bf16x8*)(vpb + vo);
    bf16x8 v1 = *(const bf16x8*)(vpb + vo + 512);
    bf16x8 v2 = *(const bf16x8*)(vpb + vo + 1024);
    bf16x8 v3 = *(const bf16x8*)(vpb + vo + 1536);

    asm volatile("s_waitcnt lgkmcnt(0)" ::: "memory");  // slab writes visible
    // A-fragment: row l16, keys of tiles 2p (quads 0-1) / 2p+1 (quads 2-3):
    // col = (quad>>1)*16 + (quad&1)*8 + j == quad*8 + j.
    bf16x8 aw = *(const bf16x8*)(&pw[w].ws[p & 1][l16][quad * 8]);

    // write NEXT iteration's weights into the other buffer (no wait needed)
    if (p < 7) {
#pragma unroll
      for (int ts = 0; ts < 2; ++ts) {
        const int t = 2 * (p + 1) + ts;
        f32x2 a = y[t][0];
        f32x2 bb = y[t][1];
        float za = __builtin_amdgcn_rcpf(a.x * a.y);
        float zb = __builtin_amdgcn_rcpf(bb.x * bb.y);
        f32x2 ra = za * __builtin_shufflevector(a, a, 1, 0);
        f32x2 rb = zb * __builtin_shufflevector(bb, bb, 1, 0);
        f32x2 wa = ra * ra;
        f32x2 wb = rb * rb;
        pw[w].ws[(p + 1) & 1][quad * 4 + 0][ts * 16 + l16] = (__bf16)wa.x;
        pw[w].ws[(p + 1) & 1][quad * 4 + 1][ts * 16 + l16] = (__bf16)wa.y;
        pw[w].ws[(p + 1) & 1][quad * 4 + 2][ts * 16 + l16] = (__bf16)wb.x;
        pw[w].ws[(p + 1) & 1][quad * 4 + 3][ts * 16 + l16] = (__bf16)wb.y;
      }
    }

    oacc[0] = __builtin_amdgcn_mfma_f32_16x16x32_bf16(aw, v0, oacc[0], 0, 0, 0);
    oacc[1] = __builtin_amdgcn_mfma_f32_16x16x32_bf16(aw, v1, oacc[1], 0, 0, 0);
    oacc[2] = __builtin_amdgcn_mfma_f32_16x16x32_bf16(aw, v2, oacc[2], 0, 0, 0);
    oacc[3] = __builtin_amdgcn_mfma_f32_16x16x32_bf16(aw, v3, oacc[3], 0, 0, 0);
  }

  // ---- phase 6: reduce partials across waves, write global ----
#pragma unroll
  for (int n = 0; n < 4; ++n)
#pragma unroll
    for (int r = 0; r < 4; ++r)
      pw[w].ex[quad * 4 + r][n * 16 + l16] = oacc[n][r];
  __syncthreads();
  {
    const int row = 2 * w + (lane >> 5);
    const int d = lane & 31;
    float v0 = 0.f, v1 = 0.f;
#pragma unroll
    for (int i = 0; i < WV; ++i) {
      v0 += pw[i].ex[row][d];
      v1 += pw[i].ex[row][d + 32];
    }
    const int off = ((b * NL + qbase + row) * NH + h) * ND + d;
    outg[off] = v0;
    outg[off + 32] = v1;
  }
}

extern "C" void kernel_launch(void* const* d_in, const int* in_sizes, int n_in,
                              void* d_out, int out_size, void* d_ws, size_t ws_size,
                              hipStream_t stream) {
  const float* q = (const float*)d_in[0];
  const float* k = (const float*)d_in[1];
  const float* v = (const float*)d_in[2];

  const size_t plane = (size_t)NB * NH * ND * NL;  // 3.15M elems, 6.29MB/plane
  __bf16* kp = (__bf16*)d_ws;
  __bf16* vp = kp + plane;

  prep<<<NB * 128 * 3 * 2, 256, 0, stream>>>(k, v, kp, vp);

  attn_poly<<<NB * NH * (NL / 16), 512, 0, stream>>>(
      q, kp, vp, (float*)d_out);
}